// Round 1
// baseline (23530.901 us; speedup 1.0000x reference)
//
#include <hip/hip_runtime.h>
#include <hip/hip_bf16.h>
#include <math.h>

// Problem constants
constexpr int B = 2, S = 2048, M = 1024, E = 512, H = 8, DHd = 64, F = 2048, V = 8192, L = 6;
constexpr int N = B * S;    // 4096 token rows
constexpr int NM = B * M;   // 2048 encoded rows

// ---------------------------------------------------------------------------
// Embedding: x[b*S+s, e] = input_embed[seq[b,s], e] + pos_embed[s, e]
// ---------------------------------------------------------------------------
__global__ __launch_bounds__(256) void k_embed(const int* __restrict__ seq,
                                               const float* __restrict__ emb,
                                               const float* __restrict__ pos,
                                               float* __restrict__ x) {
  int idx = blockIdx.x * 256 + threadIdx.x;
  if (idx >= N * E) return;
  int row = idx / E, e = idx - row * E;
  int s = row % S;
  int tok = seq[row];
  x[idx] = emb[(size_t)tok * E + e] + pos[(size_t)s * E + e];
}

// ---------------------------------------------------------------------------
// Tiled fp32 GEMM: C[r, c] = sum_k A[r,k] * W[c,k] + bias[c], optional GELU.
// A: [Nr, K] row-major, W: [Mo, K] row-major (torch weight layout).
// Grid: (Mo/64, Nr/64), 256 threads. Dims must be multiples of 64 (K of 16).
// ---------------------------------------------------------------------------
constexpr int GT = 64;
constexpr int GK = 16;

__global__ __launch_bounds__(256) void k_gemm(const float* __restrict__ A,
                                              const float* __restrict__ W,
                                              const float* __restrict__ bias,
                                              float* __restrict__ C,
                                              int K, int Mo, int act) {
  __shared__ float As[GK][GT + 4];  // +4 keeps float4 alignment of rows
  __shared__ float Ws[GK][GT + 4];
  const int tid = threadIdx.x;
  const int tx = tid & 15, ty = tid >> 4;
  const int row0 = blockIdx.y * GT, col0 = blockIdx.x * GT;
  const float* Ab = A + (size_t)row0 * K;
  const float* Wb = W + (size_t)col0 * K;
  float acc[4][4] = {};
  for (int k0 = 0; k0 < K; k0 += GK) {
#pragma unroll
    for (int i = 0; i < 4; ++i) {
      int idx = tid + i * 256;          // 0..1023
      int r = idx >> 4, kk = idx & 15;  // 64 rows x 16 k
      As[kk][r] = Ab[(size_t)r * K + (k0 + kk)];
      Ws[kk][r] = Wb[(size_t)r * K + (k0 + kk)];
    }
    __syncthreads();
#pragma unroll
    for (int kk = 0; kk < GK; ++kk) {
      float4 av = *(const float4*)&As[kk][ty * 4];
      float4 wv = *(const float4*)&Ws[kk][tx * 4];
      acc[0][0] += av.x * wv.x; acc[0][1] += av.x * wv.y; acc[0][2] += av.x * wv.z; acc[0][3] += av.x * wv.w;
      acc[1][0] += av.y * wv.x; acc[1][1] += av.y * wv.y; acc[1][2] += av.y * wv.z; acc[1][3] += av.y * wv.w;
      acc[2][0] += av.z * wv.x; acc[2][1] += av.z * wv.y; acc[2][2] += av.z * wv.z; acc[2][3] += av.z * wv.w;
      acc[3][0] += av.w * wv.x; acc[3][1] += av.w * wv.y; acc[3][2] += av.w * wv.z; acc[3][3] += av.w * wv.w;
    }
    __syncthreads();
  }
#pragma unroll
  for (int i = 0; i < 4; ++i) {
    int r = row0 + ty * 4 + i;
#pragma unroll
    for (int j = 0; j < 4; ++j) {
      int c = col0 + tx * 4 + j;
      float v = acc[i][j] + bias[c];
      if (act) v = 0.5f * v * (1.f + erff(v * 0.70710678118654752f));  // exact GELU
      C[(size_t)r * Mo + c] = v;
    }
  }
}

// ---------------------------------------------------------------------------
// Attention, one block (256 thr) per (q, h, b). Q:[B*Sq,E], K/V:[B*Sk,E].
// Head h occupies columns [h*64, h*64+64). Scores staged in LDS (Sk<=2048).
// ---------------------------------------------------------------------------
__global__ __launch_bounds__(256) void k_attn(const float* __restrict__ Q,
                                              const float* __restrict__ Kp,
                                              const float* __restrict__ Vp,
                                              float* __restrict__ O,
                                              int Sk, int causal) {
  const int q = blockIdx.x, h = blockIdx.y, b = blockIdx.z;
  const int Sq = gridDim.x;
  const int tid = threadIdx.x;
  __shared__ float sc[2048];
  __shared__ float red[4];
  __shared__ float oacc[4][64];

  const float* qrow = Q + ((size_t)b * Sq + q) * E + h * DHd;
  float4 q4[16];
  const float4* qv = (const float4*)qrow;
#pragma unroll
  for (int i = 0; i < 16; ++i) q4[i] = qv[i];

  const int kmax = causal ? (q + 1) : Sk;
  const float scale = 0.125f;  // 1/sqrt(64)

  for (int k = tid; k < kmax; k += 256) {
    const float4* kv = (const float4*)(Kp + ((size_t)b * Sk + k) * E + h * DHd);
    float s = 0.f;
#pragma unroll
    for (int i = 0; i < 16; ++i) {
      float4 kk = kv[i];
      s += q4[i].x * kk.x + q4[i].y * kk.y + q4[i].z * kk.z + q4[i].w * kk.w;
    }
    sc[k] = s * scale;
  }
  __syncthreads();

  // block max
  float m = -1e30f;
  for (int k = tid; k < kmax; k += 256) m = fmaxf(m, sc[k]);
#pragma unroll
  for (int o = 32; o; o >>= 1) m = fmaxf(m, __shfl_down(m, o, 64));
  if ((tid & 63) == 0) red[tid >> 6] = m;
  __syncthreads();
  m = fmaxf(fmaxf(red[0], red[1]), fmaxf(red[2], red[3]));

  // exp + block sum
  float ssum = 0.f;
  for (int k = tid; k < kmax; k += 256) {
    float p = __expf(sc[k] - m);
    sc[k] = p;
    ssum += p;
  }
#pragma unroll
  for (int o = 32; o; o >>= 1) ssum += __shfl_down(ssum, o, 64);
  __syncthreads();  // red reuse + sc visibility
  if ((tid & 63) == 0) red[tid >> 6] = ssum;
  __syncthreads();
  const float denom = red[0] + red[1] + red[2] + red[3];

  // P @ V: thread (sl, d) accumulates k = sl, sl+4, ...
  const int d = tid & 63, sl = tid >> 6;
  float acc = 0.f;
  for (int k = sl; k < kmax; k += 4)
    acc += sc[k] * Vp[((size_t)b * Sk + k) * E + h * DHd + d];
  oacc[sl][d] = acc;
  __syncthreads();
  if (sl == 0) {
    float o = (oacc[0][d] + oacc[1][d] + oacc[2][d] + oacc[3][d]) / denom;
    O[((size_t)b * Sq + q) * E + h * DHd + d] = o;
  }
}

// ---------------------------------------------------------------------------
// Fused residual + LayerNorm over E=512, one block per row, 2 elems/thread.
// Safe when out == xin (each element read+written by the same thread).
// ---------------------------------------------------------------------------
__global__ __launch_bounds__(256) void k_res_ln(const float* __restrict__ xin,
                                                const float* __restrict__ r,
                                                const float* __restrict__ g,
                                                const float* __restrict__ beta,
                                                float* __restrict__ out,
                                                int has_res) {
  __shared__ float red[4];
  const int row = blockIdx.x, tid = threadIdx.x;
  const float* xr = xin + (size_t)row * E;
  float v0 = xr[tid], v1 = xr[tid + 256];
  if (has_res) {
    const float* rr = r + (size_t)row * E;
    v0 += rr[tid];
    v1 += rr[tid + 256];
  }
  float s = v0 + v1;
#pragma unroll
  for (int o = 32; o; o >>= 1) s += __shfl_down(s, o, 64);
  if ((tid & 63) == 0) red[tid >> 6] = s;
  __syncthreads();
  const float mean = (red[0] + red[1] + red[2] + red[3]) * (1.f / E);
  float d0 = v0 - mean, d1 = v1 - mean;
  float vs = d0 * d0 + d1 * d1;
#pragma unroll
  for (int o = 32; o; o >>= 1) vs += __shfl_down(vs, o, 64);
  __syncthreads();
  if ((tid & 63) == 0) red[tid >> 6] = vs;
  __syncthreads();
  const float var = (red[0] + red[1] + red[2] + red[3]) * (1.f / E);
  const float inv = rsqrtf(var + 1e-5f);
  float* orow = out + (size_t)row * E;
  orow[tid] = d0 * inv * g[tid] + beta[tid];
  orow[tid + 256] = d1 * inv * g[tid + 256] + beta[tid + 256];
}

// ---------------------------------------------------------------------------
extern "C" void kernel_launch(void* const* d_in, const int* in_sizes, int n_in,
                              void* d_out, int out_size, void* d_ws, size_t ws_size,
                              hipStream_t stream) {
  const float* encoded      = (const float*)d_in[0];
  const int*   seq          = (const int*)d_in[1];
  const float* input_embed  = (const float*)d_in[2];
  const float* pos_embed    = (const float*)d_in[3];
  const float* output_bias  = (const float*)d_in[4];
  const float* self_in_w    = (const float*)d_in[5];
  const float* self_in_b    = (const float*)d_in[6];
  const float* self_out_w   = (const float*)d_in[7];
  const float* self_out_b   = (const float*)d_in[8];
  const float* cross_in_w   = (const float*)d_in[9];
  const float* cross_in_b   = (const float*)d_in[10];
  const float* cross_out_w  = (const float*)d_in[11];
  const float* cross_out_b  = (const float*)d_in[12];
  const float* self_norm_g  = (const float*)d_in[13];
  const float* self_norm_b  = (const float*)d_in[14];
  const float* cross_norm_g = (const float*)d_in[15];
  const float* cross_norm_b = (const float*)d_in[16];
  const float* mlp_norm_g   = (const float*)d_in[17];
  const float* mlp_norm_b   = (const float*)d_in[18];
  const float* lin1_w       = (const float*)d_in[19];
  const float* lin1_b       = (const float*)d_in[20];
  const float* lin2_w       = (const float*)d_in[21];
  const float* lin2_b       = (const float*)d_in[22];
  const float* final_norm_g = (const float*)d_in[23];
  const float* final_norm_b = (const float*)d_in[24];

  float* out = (float*)d_out;
  float* ws = (float*)d_ws;

  // Stream buffers in ws (2 x 8 MB). Scratch lives inside d_out (134 MB),
  // which is fully overwritten by the final logits GEMM.
  float* xs = ws;                        // [N, E] current stream
  float* ys = xs + (size_t)N * E;        // [N, E] post-self-LN
  float* qb = out;                       // [N, E]
  float* kb = qb + (size_t)N * E;        // [N, E] (cross uses first NM rows)
  float* vb = kb + (size_t)N * E;        // [N, E]
  float* cb = vb + (size_t)N * E;        // [N, E] attention context
  float* hb = cb + (size_t)N * E;        // [N, F] MLP hidden (4*N*E floats)

  const dim3 blk(256);
  const dim3 gNE(E / GT, N / GT);    // [N,E] gemm
  const dim3 gME(E / GT, NM / GT);   // [NM,E] gemm
  const dim3 gNF(F / GT, N / GT);    // [N,F] gemm
  const dim3 gNV(V / GT, N / GT);    // [N,V] gemm

  k_embed<<<dim3((N * E + 255) / 256), blk, 0, stream>>>(seq, input_embed, pos_embed, xs);

  for (int l = 0; l < L; ++l) {
    const float* siw = self_in_w + (size_t)l * 3 * E * E;
    const float* sib = self_in_b + (size_t)l * 3 * E;
    // --- self attention (causal) ---
    k_gemm<<<gNE, blk, 0, stream>>>(xs, siw,               sib,         qb, E, E, 0);
    k_gemm<<<gNE, blk, 0, stream>>>(xs, siw + E * E,       sib + E,     kb, E, E, 0);
    k_gemm<<<gNE, blk, 0, stream>>>(xs, siw + 2 * E * E,   sib + 2 * E, vb, E, E, 0);
    k_attn<<<dim3(S, H, B), blk, 0, stream>>>(qb, kb, vb, cb, S, 1);
    k_gemm<<<gNE, blk, 0, stream>>>(cb, self_out_w + (size_t)l * E * E, self_out_b + (size_t)l * E, qb, E, E, 0);
    k_res_ln<<<dim3(N), blk, 0, stream>>>(xs, qb, self_norm_g + (size_t)l * E, self_norm_b + (size_t)l * E, ys, 1);

    // --- cross attention (keys/values from encoded) ---
    const float* ciw = cross_in_w + (size_t)l * 3 * E * E;
    const float* cib = cross_in_b + (size_t)l * 3 * E;
    k_gemm<<<gNE, blk, 0, stream>>>(ys, ciw,              cib,         qb, E, E, 0);
    k_gemm<<<gME, blk, 0, stream>>>(encoded, ciw + E * E, cib + E,     kb, E, E, 0);
    k_gemm<<<gME, blk, 0, stream>>>(encoded, ciw + 2 * E * E, cib + 2 * E, vb, E, E, 0);
    k_attn<<<dim3(S, H, B), blk, 0, stream>>>(qb, kb, vb, cb, M, 0);
    k_gemm<<<gNE, blk, 0, stream>>>(cb, cross_out_w + (size_t)l * E * E, cross_out_b + (size_t)l * E, qb, E, E, 0);
    k_res_ln<<<dim3(N), blk, 0, stream>>>(ys, qb, cross_norm_g + (size_t)l * E, cross_norm_b + (size_t)l * E, xs, 1);

    // --- MLP ---
    k_gemm<<<gNF, blk, 0, stream>>>(xs, lin1_w + (size_t)l * F * E, lin1_b + (size_t)l * F, hb, E, F, 1);
    k_gemm<<<gNE, blk, 0, stream>>>(hb, lin2_w + (size_t)l * E * F, lin2_b + (size_t)l * E, qb, F, E, 0);
    k_res_ln<<<dim3(N), blk, 0, stream>>>(xs, qb, mlp_norm_g + (size_t)l * E, mlp_norm_b + (size_t)l * E, xs, 1);
  }

  // final norm (no residual), then logits = xs @ input_embed^T + output_bias
  k_res_ln<<<dim3(N), blk, 0, stream>>>(xs, nullptr, final_norm_g, final_norm_b, xs, 0);
  k_gemm<<<gNV, blk, 0, stream>>>(xs, input_embed, output_bias, out, E, V, 0);
}

// Round 2
// 2020.514 us; speedup vs baseline: 11.6460x; 11.6460x over previous
//
#include <hip/hip_runtime.h>
#include <math.h>

typedef unsigned short u16;
typedef __attribute__((ext_vector_type(8))) unsigned short u16x8;
typedef __attribute__((ext_vector_type(8))) __bf16 bf16x8;
typedef __attribute__((ext_vector_type(4))) float f32x4;

constexpr int Bc = 2, Sc = 2048, Mc = 1024, Ec = 512, Hc = 8, DH = 64, Fc = 2048, Vc = 8192, Lc = 6;
constexpr int Nc = Bc * Sc;    // 4096 decoder rows
constexpr int NMc = Bc * Mc;   // 2048 encoder rows

__device__ __forceinline__ u16 f2b(float f) {
  union { float f; unsigned u; } v; v.f = f;
  unsigned r = v.u + 0x7FFFu + ((v.u >> 16) & 1u);   // RNE
  return (u16)(r >> 16);
}

__device__ __forceinline__ f32x4 mfma16(bf16x8 a, bf16x8 b, f32x4 c) {
  return __builtin_amdgcn_mfma_f32_16x16x32_bf16(a, b, c, 0, 0, 0);
}

// ---------------------------------------------------------------------------
// f32 -> bf16 bulk convert (n multiple of 4)
// ---------------------------------------------------------------------------
__global__ __launch_bounds__(256) void k_cvt(const float* __restrict__ s,
                                             u16* __restrict__ d, int n4) {
  int i = blockIdx.x * 256 + threadIdx.x;
  if (i >= n4) return;
  float4 v = ((const float4*)s)[i];
  u16 o0 = f2b(v.x), o1 = f2b(v.y), o2 = f2b(v.z), o3 = f2b(v.w);
  unsigned lo = (unsigned)o0 | ((unsigned)o1 << 16);
  unsigned hi = (unsigned)o2 | ((unsigned)o3 << 16);
  ((uint2*)d)[i] = make_uint2(lo, hi);
}

// ---------------------------------------------------------------------------
// Embedding: fp32 + bf16 outputs
// ---------------------------------------------------------------------------
__global__ __launch_bounds__(256) void k_embed(const int* __restrict__ seq,
                                               const float* __restrict__ emb,
                                               const float* __restrict__ pos,
                                               float* __restrict__ x,
                                               u16* __restrict__ xb) {
  int idx = blockIdx.x * 256 + threadIdx.x;   // exactly N*E = 2^21
  int row = idx >> 9;          // E = 512
  int e = idx & 511;
  int s = row & (Sc - 1);      // row % S
  float v = emb[(size_t)seq[row] * Ec + e] + pos[(size_t)s * Ec + e];
  x[idx] = v;
  xb[idx] = f2b(v);
}

// ---------------------------------------------------------------------------
// bf16 MFMA GEMM: C[r,c] = sum_k A[r,k]*W[c,k] + bias[c]; optional GELU.
// A [Nr,K] bf16, W [Mo,K] bf16 (torch layout). Tiles 128x128, BK=64,
// 256 thr = 4 waves (2x2 of 64x64), 4x4 16x16x32 MFMA frags per wave.
// Outputs: fp32 (C32) and/or bf16 (Cb), either may be null.
// ---------------------------------------------------------------------------
template <int ACT>
__global__ __launch_bounds__(256) void k_gemm_bf(const u16* __restrict__ A,
                                                 const u16* __restrict__ W,
                                                 const float* __restrict__ bias,
                                                 float* __restrict__ C32,
                                                 u16* __restrict__ Cb,
                                                 int K, int Mo) {
  __shared__ __attribute__((aligned(16))) u16 As[128 * 64];
  __shared__ __attribute__((aligned(16))) u16 Bs[128 * 64];
  const int tid = threadIdx.x;
  const int w = tid >> 6, l = tid & 63, l15 = l & 15, l4 = l >> 4;
  const int wr = (w >> 1) * 64, wc = (w & 1) * 64;
  const size_t row0 = (size_t)blockIdx.y * 128, col0 = (size_t)blockIdx.x * 128;
  const u16* Ab = A + row0 * K;
  const u16* Wb = W + col0 * K;
  const int trow = tid >> 3, tch = tid & 7;
  f32x4 acc[4][4] = {};

  for (int k0 = 0; k0 < K; k0 += 64) {
    __syncthreads();
#pragma unroll
    for (int i = 0; i < 4; ++i) {
      int lb = w * 1024 + i * 4096;              // wave-uniform LDS byte base
      int row = i * 32 + trow;
      const u16* ga = Ab + (size_t)row * K + k0 + tch * 8;
      const u16* gw = Wb + (size_t)row * K + k0 + tch * 8;
      __builtin_amdgcn_global_load_lds((__attribute__((address_space(1))) void*)ga,
          (__attribute__((address_space(3))) void*)((char*)As + lb), 16, 0, 0);
      __builtin_amdgcn_global_load_lds((__attribute__((address_space(1))) void*)gw,
          (__attribute__((address_space(3))) void*)((char*)Bs + lb), 16, 0, 0);
    }
    __syncthreads();
#pragma unroll
    for (int ks = 0; ks < 2; ++ks) {
      bf16x8 af[4], bfr[4];
#pragma unroll
      for (int m = 0; m < 4; ++m)
        af[m] = *(const bf16x8*)&As[(wr + m * 16 + l15) * 64 + ks * 32 + l4 * 8];
#pragma unroll
      for (int n = 0; n < 4; ++n)
        bfr[n] = *(const bf16x8*)&Bs[(wc + n * 16 + l15) * 64 + ks * 32 + l4 * 8];
#pragma unroll
      for (int m = 0; m < 4; ++m)
#pragma unroll
        for (int n = 0; n < 4; ++n)
          acc[m][n] = mfma16(af[m], bfr[n], acc[m][n]);
    }
  }
  // epilogue: D layout col = l&15, row = (l>>4)*4 + reg
#pragma unroll
  for (int n = 0; n < 4; ++n) {
    size_t col = col0 + wc + n * 16 + l15;
    float bv = bias[col];
#pragma unroll
    for (int m = 0; m < 4; ++m)
#pragma unroll
      for (int r = 0; r < 4; ++r) {
        size_t row = row0 + wr + m * 16 + l4 * 4 + r;
        float v = acc[m][n][r] + bv;
        if (ACT) v = 0.5f * v * (1.f + erff(v * 0.70710678118654752f));
        if (C32) C32[row * Mo + col] = v;
        if (Cb) Cb[row * Mo + col] = f2b(v);
      }
  }
}

// ---------------------------------------------------------------------------
// Flash attention, bf16 MFMA. Grid (Sq/64, H, B), 256 thr = 4 waves.
// Wave w owns q rows [qt0+w*16, +16). K/V tiles of 64 staged in LDS
// (rows padded to 72 elems = 144B -> conflict-light). Online softmax.
// ---------------------------------------------------------------------------
__global__ __launch_bounds__(256) void k_flash(const u16* __restrict__ Qp, int sq,
                                               const u16* __restrict__ Kp,
                                               const u16* __restrict__ Vp, int skv,
                                               u16* __restrict__ Op, int so,
                                               int Sq, int Sk, int causal) {
  __shared__ __attribute__((aligned(16))) u16 Kst[64 * 72];
  __shared__ __attribute__((aligned(16))) u16 Vt[64 * 72];   // [d][k]
  __shared__ __attribute__((aligned(16))) u16 Pl[4][16 * 72];
  const int tid = threadIdx.x;
  const int w = tid >> 6, l = tid & 63, l15 = l & 15, l4 = l >> 4;
  const int qt0 = blockIdx.x * 64;
  const int h = blockIdx.y, b = blockIdx.z;
  const u16* Qb = Qp + (size_t)b * Sq * sq + h * DH;
  const u16* Kb = Kp + (size_t)b * Sk * skv + h * DH;
  const u16* Vb = Vp + (size_t)b * Sk * skv + h * DH;

  bf16x8 qf[2];
  {
    int qrow = qt0 + w * 16 + l15;
    const u16* qp0 = Qb + (size_t)qrow * sq + l4 * 8;
    qf[0] = *(const bf16x8*)(qp0);
    qf[1] = *(const bf16x8*)(qp0 + 32);
  }
  f32x4 oacc[4] = {};
  float Mx[4], Ls[4];
#pragma unroll
  for (int r = 0; r < 4; ++r) { Mx[r] = -3e38f; Ls[r] = 0.f; }

  const float CSC = 0.18033688011112042f;  // 1/sqrt(64) * log2(e)
  const int kend = causal ? (qt0 + 64) : Sk;

  for (int kt = 0; kt < kend; kt += 64) {
    __syncthreads();
    // stage K tile [64][64] (row-major, padded)
#pragma unroll
    for (int i = 0; i < 2; ++i) {
      int row = i * 32 + (tid >> 3);
      int ch = tid & 7;
      u16x8 kd = *(const u16x8*)(Kb + (size_t)(kt + row) * skv + ch * 8);
      *(u16x8*)&Kst[row * 72 + ch * 8] = kd;
    }
    // stage V transposed: Vt[d][k]
    {
      int kk2 = tid >> 3, dblk = tid & 7;
      const u16* vp0 = Vb + (size_t)(kt + 2 * kk2) * skv + dblk * 8;
      u16x8 va = *(const u16x8*)vp0;
      u16x8 vbb = *(const u16x8*)(vp0 + skv);
#pragma unroll
      for (int j = 0; j < 8; ++j) {
        unsigned pk = (unsigned)va[j] | ((unsigned)vbb[j] << 16);
        *(unsigned*)&Vt[(dblk * 8 + j) * 72 + 2 * kk2] = pk;
      }
    }
    __syncthreads();

    // S = Q K^T  (16 q rows x 64 k cols per wave)
    f32x4 sf[4] = {};
#pragma unroll
    for (int n = 0; n < 4; ++n)
#pragma unroll
      for (int s2 = 0; s2 < 2; ++s2) {
        bf16x8 kf = *(const bf16x8*)&Kst[(n * 16 + l15) * 72 + s2 * 32 + l4 * 8];
        sf[n] = mfma16(qf[s2], kf, sf[n]);
      }

    if (causal && (kt + 63 > qt0 + w * 16)) {
#pragma unroll
      for (int n = 0; n < 4; ++n)
#pragma unroll
        for (int r = 0; r < 4; ++r) {
          int qrow = qt0 + w * 16 + l4 * 4 + r;
          int kcol = kt + n * 16 + l15;
          if (kcol > qrow) sf[n][r] = -3e38f;
        }
    }

    // online softmax: row stats across 16-lane group (cols) + in-lane frags
    float al[4];
#pragma unroll
    for (int r = 0; r < 4; ++r) {
      float tm = fmaxf(fmaxf(sf[0][r], sf[1][r]), fmaxf(sf[2][r], sf[3][r]));
      tm = fmaxf(tm, __shfl_xor(tm, 1, 64));
      tm = fmaxf(tm, __shfl_xor(tm, 2, 64));
      tm = fmaxf(tm, __shfl_xor(tm, 4, 64));
      tm = fmaxf(tm, __shfl_xor(tm, 8, 64));
      float Mn = fmaxf(Mx[r], tm);
      al[r] = exp2f((Mx[r] - Mn) * CSC);
      Mx[r] = Mn;
    }
    float rs[4] = {0.f, 0.f, 0.f, 0.f};
    u16* Pw = Pl[w];
#pragma unroll
    for (int n = 0; n < 4; ++n)
#pragma unroll
      for (int r = 0; r < 4; ++r) {
        float p = exp2f((sf[n][r] - Mx[r]) * CSC);
        rs[r] += p;
        Pw[(l4 * 4 + r) * 72 + n * 16 + l15] = f2b(p);
      }
#pragma unroll
    for (int r = 0; r < 4; ++r) {
      float t2 = rs[r];
      t2 += __shfl_xor(t2, 1, 64);
      t2 += __shfl_xor(t2, 2, 64);
      t2 += __shfl_xor(t2, 4, 64);
      t2 += __shfl_xor(t2, 8, 64);
      Ls[r] = Ls[r] * al[r] + t2;
    }
#pragma unroll
    for (int n2 = 0; n2 < 4; ++n2)
#pragma unroll
      for (int r = 0; r < 4; ++r) oacc[n2][r] *= al[r];
    __syncthreads();  // P visibility across lanes (and type-pun ordering)

    // O += P V
#pragma unroll
    for (int ks = 0; ks < 2; ++ks) {
      bf16x8 pf = *(const bf16x8*)&Pw[l15 * 72 + ks * 32 + l4 * 8];
#pragma unroll
      for (int n2 = 0; n2 < 4; ++n2) {
        bf16x8 vf = *(const bf16x8*)&Vt[(n2 * 16 + l15) * 72 + ks * 32 + l4 * 8];
        oacc[n2] = mfma16(pf, vf, oacc[n2]);
      }
    }
  }

  u16* Ob = Op + (size_t)b * Sq * so + h * DH;
#pragma unroll
  for (int n2 = 0; n2 < 4; ++n2)
#pragma unroll
    for (int r = 0; r < 4; ++r) {
      int qrow = qt0 + w * 16 + l4 * 4 + r;
      Ob[(size_t)qrow * so + n2 * 16 + l15] = f2b(oacc[n2][r] / Ls[r]);
    }
}

// ---------------------------------------------------------------------------
// Fused residual + LayerNorm (fp32), dual fp32/bf16 outputs.
// ---------------------------------------------------------------------------
__global__ __launch_bounds__(256) void k_res_ln(const float* __restrict__ xin,
                                                const float* __restrict__ rres,
                                                const float* __restrict__ g,
                                                const float* __restrict__ bet,
                                                float* __restrict__ outf,
                                                u16* __restrict__ outb,
                                                int has_res) {
  __shared__ float red[4];
  const int row = blockIdx.x, tid = threadIdx.x;
  const float* xr = xin + (size_t)row * Ec;
  float v0 = xr[tid], v1 = xr[tid + 256];
  if (has_res) {
    const float* rr = rres + (size_t)row * Ec;
    v0 += rr[tid];
    v1 += rr[tid + 256];
  }
  float s = v0 + v1;
#pragma unroll
  for (int o = 32; o; o >>= 1) s += __shfl_down(s, o, 64);
  if ((tid & 63) == 0) red[tid >> 6] = s;
  __syncthreads();
  const float mean = (red[0] + red[1] + red[2] + red[3]) * (1.f / Ec);
  float d0 = v0 - mean, d1 = v1 - mean;
  float vs = d0 * d0 + d1 * d1;
#pragma unroll
  for (int o = 32; o; o >>= 1) vs += __shfl_down(vs, o, 64);
  __syncthreads();
  if ((tid & 63) == 0) red[tid >> 6] = vs;
  __syncthreads();
  const float var = (red[0] + red[1] + red[2] + red[3]) * (1.f / Ec);
  const float inv = rsqrtf(var + 1e-5f);
  float o0 = d0 * inv * g[tid] + bet[tid];
  float o1 = d1 * inv * g[tid + 256] + bet[tid + 256];
  float* orow = outf + (size_t)row * Ec;
  orow[tid] = o0;
  orow[tid + 256] = o1;
  if (outb) {
    u16* brow = outb + (size_t)row * Ec;
    brow[tid] = f2b(o0);
    brow[tid + 256] = f2b(o1);
  }
}

// ---------------------------------------------------------------------------
extern "C" void kernel_launch(void* const* d_in, const int* in_sizes, int n_in,
                              void* d_out, int out_size, void* d_ws, size_t ws_size,
                              hipStream_t stream) {
  const float* encoded      = (const float*)d_in[0];
  const int*   seq          = (const int*)d_in[1];
  const float* input_embed  = (const float*)d_in[2];
  const float* pos_embed    = (const float*)d_in[3];
  const float* output_bias  = (const float*)d_in[4];
  const float* self_in_w    = (const float*)d_in[5];
  const float* self_in_b    = (const float*)d_in[6];
  const float* self_out_w   = (const float*)d_in[7];
  const float* self_out_b   = (const float*)d_in[8];
  const float* cross_in_w   = (const float*)d_in[9];
  const float* cross_in_b   = (const float*)d_in[10];
  const float* cross_out_w  = (const float*)d_in[11];
  const float* cross_out_b  = (const float*)d_in[12];
  const float* self_norm_g  = (const float*)d_in[13];
  const float* self_norm_b  = (const float*)d_in[14];
  const float* cross_norm_g = (const float*)d_in[15];
  const float* cross_norm_b = (const float*)d_in[16];
  const float* mlp_norm_g   = (const float*)d_in[17];
  const float* mlp_norm_b   = (const float*)d_in[18];
  const float* lin1_w       = (const float*)d_in[19];
  const float* lin1_b       = (const float*)d_in[20];
  const float* lin2_w       = (const float*)d_in[21];
  const float* lin2_b       = (const float*)d_in[22];
  const float* final_norm_g = (const float*)d_in[23];
  const float* final_norm_b = (const float*)d_in[24];

  // ---- scratch layout inside d_out (fully overwritten by final logits GEMM;
  //      the final GEMM reads only d_ws + output_bias, so no aliasing hazard).
  char* oc = (char*)d_out;
  auto take = [&](size_t bytes) { char* p = oc; oc += bytes; return p; };
  u16* wsi  = (u16*)take((size_t)Lc * 3 * Ec * Ec * 2);
  u16* wso  = (u16*)take((size_t)Lc * Ec * Ec * 2);
  u16* wci  = (u16*)take((size_t)Lc * 3 * Ec * Ec * 2);
  u16* wco  = (u16*)take((size_t)Lc * Ec * Ec * 2);
  u16* wl1  = (u16*)take((size_t)Lc * Fc * Ec * 2);
  u16* wl2  = (u16*)take((size_t)Lc * Ec * Fc * 2);
  u16* encb = (u16*)take((size_t)NMc * Ec * 2);
  float* xs  = (float*)take((size_t)Nc * Ec * 4);
  float* ys  = (float*)take((size_t)Nc * Ec * 4);
  float* tmp = (float*)take((size_t)Nc * Ec * 4);
  u16* xbf  = (u16*)take((size_t)Nc * Ec * 2);
  u16* qkvb = (u16*)take((size_t)Nc * 3 * Ec * 2);
  u16* ctxb = (u16*)take((size_t)Nc * Ec * 2);
  u16* qxb  = (u16*)take((size_t)Nc * Ec * 2);
  u16* kvb  = (u16*)take((size_t)NMc * 2 * Ec * 2);
  u16* hbf  = (u16*)take((size_t)Nc * Fc * 2);
  // ---- final-GEMM operands in d_ws (12.6 MB)
  u16* xfb  = (u16*)d_ws;
  u16* embb = (u16*)((char*)d_ws + (size_t)Nc * Ec * 2);

  const dim3 blk(256);
  auto cvt = [&](const float* s, u16* d, size_t n) {
    int n4 = (int)(n / 4);
    k_cvt<<<dim3((n4 + 255) / 256), blk, 0, stream>>>(s, d, n4);
  };
  cvt(self_in_w, wsi, (size_t)Lc * 3 * Ec * Ec);
  cvt(self_out_w, wso, (size_t)Lc * Ec * Ec);
  cvt(cross_in_w, wci, (size_t)Lc * 3 * Ec * Ec);
  cvt(cross_out_w, wco, (size_t)Lc * Ec * Ec);
  cvt(lin1_w, wl1, (size_t)Lc * Fc * Ec);
  cvt(lin2_w, wl2, (size_t)Lc * Ec * Fc);
  cvt(input_embed, embb, (size_t)Vc * Ec);
  cvt(encoded, encb, (size_t)NMc * Ec);

  k_embed<<<dim3(Nc * Ec / 256), blk, 0, stream>>>(seq, input_embed, pos_embed, xs, xbf);

  const dim3 gAttn(Sc / 64, Hc, Bc);
  for (int l = 0; l < Lc; ++l) {
    const u16* wsi_l = wsi + (size_t)l * 3 * Ec * Ec;
    const u16* wci_l = wci + (size_t)l * 3 * Ec * Ec;
    // self attention
    k_gemm_bf<0><<<dim3(3 * Ec / 128, Nc / 128), blk, 0, stream>>>(
        xbf, wsi_l, self_in_b + (size_t)l * 3 * Ec, nullptr, qkvb, Ec, 3 * Ec);
    k_flash<<<gAttn, blk, 0, stream>>>(qkvb, 3 * Ec, qkvb + Ec, qkvb + 2 * Ec, 3 * Ec,
                                       ctxb, Ec, Sc, Sc, 1);
    k_gemm_bf<0><<<dim3(Ec / 128, Nc / 128), blk, 0, stream>>>(
        ctxb, wso + (size_t)l * Ec * Ec, self_out_b + (size_t)l * Ec, tmp, nullptr, Ec, Ec);
    k_res_ln<<<dim3(Nc), blk, 0, stream>>>(xs, tmp, self_norm_g + (size_t)l * Ec,
                                           self_norm_b + (size_t)l * Ec, ys, xbf, 1);
    // cross attention
    k_gemm_bf<0><<<dim3(Ec / 128, Nc / 128), blk, 0, stream>>>(
        xbf, wci_l, cross_in_b + (size_t)l * 3 * Ec, nullptr, qxb, Ec, Ec);
    k_gemm_bf<0><<<dim3(2 * Ec / 128, NMc / 128), blk, 0, stream>>>(
        encb, wci_l + (size_t)Ec * Ec, cross_in_b + (size_t)l * 3 * Ec + Ec,
        nullptr, kvb, Ec, 2 * Ec);
    k_flash<<<gAttn, blk, 0, stream>>>(qxb, Ec, kvb, kvb + Ec, 2 * Ec,
                                       ctxb, Ec, Sc, Mc, 0);
    k_gemm_bf<0><<<dim3(Ec / 128, Nc / 128), blk, 0, stream>>>(
        ctxb, wco + (size_t)l * Ec * Ec, cross_out_b + (size_t)l * Ec, tmp, nullptr, Ec, Ec);
    k_res_ln<<<dim3(Nc), blk, 0, stream>>>(ys, tmp, cross_norm_g + (size_t)l * Ec,
                                           cross_norm_b + (size_t)l * Ec, xs, xbf, 1);
    // MLP
    k_gemm_bf<1><<<dim3(Fc / 128, Nc / 128), blk, 0, stream>>>(
        xbf, wl1 + (size_t)l * Fc * Ec, lin1_b + (size_t)l * Fc, nullptr, hbf, Ec, Fc);
    k_gemm_bf<0><<<dim3(Ec / 128, Nc / 128), blk, 0, stream>>>(
        hbf, wl2 + (size_t)l * Ec * Fc, lin2_b + (size_t)l * Ec, tmp, nullptr, Fc, Ec);
    k_res_ln<<<dim3(Nc), blk, 0, stream>>>(xs, tmp, mlp_norm_g + (size_t)l * Ec,
                                           mlp_norm_b + (size_t)l * Ec, xs, xbf, 1);
  }

  // final norm -> bf16 into ws; logits = x @ emb^T + bias over all of d_out
  k_res_ln<<<dim3(Nc), blk, 0, stream>>>(xs, nullptr, final_norm_g, final_norm_b, xs, xfb, 0);
  k_gemm_bf<0><<<dim3(Vc / 128, Nc / 128), blk, 0, stream>>>(
      xfb, embb, output_bias, (float*)d_out, nullptr, Ec, Vc);
}

// Round 3
// 1496.221 us; speedup vs baseline: 15.7269x; 1.3504x over previous
//
#include <hip/hip_runtime.h>
#include <math.h>

typedef unsigned short u16;
typedef __attribute__((ext_vector_type(8))) unsigned short u16x8;
typedef __attribute__((ext_vector_type(8))) __bf16 bf16x8;
typedef __attribute__((ext_vector_type(4))) float f32x4;

constexpr int Bc = 2, Sc = 2048, Mc = 1024, Ec = 512, Hc = 8, DH = 64, Fc = 2048, Vc = 8192, Lc = 6;
constexpr int Nc = Bc * Sc;    // 4096 decoder rows
constexpr int NMc = Bc * Mc;   // 2048 encoder rows

__device__ __forceinline__ u16 f2b(float f) {
  union { float f; unsigned u; } v; v.f = f;
  unsigned r = v.u + 0x7FFFu + ((v.u >> 16) & 1u);   // RNE
  return (u16)(r >> 16);
}

__device__ __forceinline__ f32x4 mfma16(bf16x8 a, bf16x8 b, f32x4 c) {
  return __builtin_amdgcn_mfma_f32_16x16x32_bf16(a, b, c, 0, 0, 0);
}

// ---------------------------------------------------------------------------
// f32 -> bf16 bulk convert
// ---------------------------------------------------------------------------
__global__ __launch_bounds__(256) void k_cvt(const float* __restrict__ s,
                                             u16* __restrict__ d, int n4) {
  int i = blockIdx.x * 256 + threadIdx.x;
  if (i >= n4) return;
  float4 v = ((const float4*)s)[i];
  unsigned lo = (unsigned)f2b(v.x) | ((unsigned)f2b(v.y) << 16);
  unsigned hi = (unsigned)f2b(v.z) | ((unsigned)f2b(v.w) << 16);
  ((uint2*)d)[i] = make_uint2(lo, hi);
}

// ---------------------------------------------------------------------------
// Embedding: fp32 + bf16 outputs
// ---------------------------------------------------------------------------
__global__ __launch_bounds__(256) void k_embed(const int* __restrict__ seq,
                                               const float* __restrict__ emb,
                                               const float* __restrict__ pos,
                                               float* __restrict__ x,
                                               u16* __restrict__ xb) {
  int idx = blockIdx.x * 256 + threadIdx.x;
  int row = idx >> 9, e = idx & 511;
  int s = row & (Sc - 1);
  float v = emb[(size_t)seq[row] * Ec + e] + pos[(size_t)s * Ec + e];
  x[idx] = v;
  xb[idx] = f2b(v);
}

// ---------------------------------------------------------------------------
// bf16 MFMA GEMM, swizzled LDS (byte ^= ((row&7)^(row>>3))<<4 within 128B row)
// staged via global_load_lds with pre-swizzled per-lane source.
// Tiles BM x BN, BK=64, 4 waves in 2x2 quadrants of (BM/2)x(BN/2).
// ---------------------------------------------------------------------------
template <int BM, int BN, int ACT>
__global__ __launch_bounds__(256) void k_gemm_bf(const u16* __restrict__ A,
                                                 const u16* __restrict__ W,
                                                 const float* __restrict__ bias,
                                                 float* __restrict__ C32,
                                                 u16* __restrict__ Cb,
                                                 int K, int Mo) {
  constexpr int WM = BM / 2, WN = BN / 2, FM = WM / 16, FN = WN / 16;
  __shared__ __attribute__((aligned(16))) u16 As[BM * 64];
  __shared__ __attribute__((aligned(16))) u16 Bs[BN * 64];
  const int tid = threadIdx.x;
  const int w = tid >> 6, l = tid & 63, l15 = l & 15, l4 = l >> 4;
  const int lr = l >> 3, lc = l & 7;
  const int wr = (w >> 1) * WM, wc = (w & 1) * WN;
  const size_t row0 = (size_t)blockIdx.y * BM, col0 = (size_t)blockIdx.x * BN;
  const u16* Ab = A + row0 * K;
  const u16* Wb = W + col0 * K;
  f32x4 acc[FM][FN] = {};

  for (int k0 = 0; k0 < K; k0 += 64) {
    __syncthreads();
#pragma unroll
    for (int i = 0; i < BM / 32; ++i) {
      int row = i * 32 + w * 8 + lr;
      int sw = lr ^ ((i * 4 + w) & 7);
      const u16* ga = Ab + (size_t)row * K + k0 + ((lc ^ sw) & 7) * 8;
      __builtin_amdgcn_global_load_lds((const __attribute__((address_space(1))) void*)ga,
          (__attribute__((address_space(3))) void*)((char*)As + (i * 32 + w * 8) * 128), 16, 0, 0);
    }
#pragma unroll
    for (int i = 0; i < BN / 32; ++i) {
      int row = i * 32 + w * 8 + lr;
      int sw = lr ^ ((i * 4 + w) & 7);
      const u16* gw = Wb + (size_t)row * K + k0 + ((lc ^ sw) & 7) * 8;
      __builtin_amdgcn_global_load_lds((const __attribute__((address_space(1))) void*)gw,
          (__attribute__((address_space(3))) void*)((char*)Bs + (i * 32 + w * 8) * 128), 16, 0, 0);
    }
    __syncthreads();
#pragma unroll
    for (int ks = 0; ks < 2; ++ks) {
      bf16x8 af[FM], bfr[FN];
#pragma unroll
      for (int m = 0; m < FM; ++m) {
        int ra = wr + m * 16 + l15;
        int sw = (l15 & 7) ^ ((wr / 8 + 2 * m + (l15 >> 3)) & 7);
        af[m] = *(const bf16x8*)&As[ra * 64 + ((ks * 32 + l4 * 8) ^ (sw * 8))];
      }
#pragma unroll
      for (int n = 0; n < FN; ++n) {
        int rb = wc + n * 16 + l15;
        int sw = (l15 & 7) ^ ((wc / 8 + 2 * n + (l15 >> 3)) & 7);
        bfr[n] = *(const bf16x8*)&Bs[rb * 64 + ((ks * 32 + l4 * 8) ^ (sw * 8))];
      }
#pragma unroll
      for (int m = 0; m < FM; ++m)
#pragma unroll
        for (int n = 0; n < FN; ++n)
          acc[m][n] = mfma16(af[m], bfr[n], acc[m][n]);
    }
  }
#pragma unroll
  for (int n = 0; n < FN; ++n) {
    size_t col = col0 + wc + n * 16 + l15;
    float bv = bias[col];
#pragma unroll
    for (int m = 0; m < FM; ++m)
#pragma unroll
      for (int r = 0; r < 4; ++r) {
        size_t row = row0 + wr + m * 16 + l4 * 4 + r;
        float v = acc[m][n][r] + bv;
        if (ACT) v = 0.5f * v * (1.f + erff(v * 0.70710678118654752f));
        if (C32) C32[row * Mo + col] = v;
        if (Cb) Cb[row * Mo + col] = f2b(v);
      }
  }
}

// ---------------------------------------------------------------------------
// Flash attention, bf16 MFMA, double-buffered K/V, swizzled LDS.
// Grid (Sq/64, H, B), 256 thr = 4 waves; wave w owns q rows [qt0+16w, +16).
// K staged via global_load_lds (pre-swizzled source); V via regs -> swizzled
// transpose ds_write (issue-early / write-late); one barrier per k-tile.
// ---------------------------------------------------------------------------
__global__ __launch_bounds__(256) void k_flash(const u16* __restrict__ Qp, int sq,
                                               const u16* __restrict__ Kp,
                                               const u16* __restrict__ Vp, int skv,
                                               u16* __restrict__ Op, int so,
                                               int Sq, int Sk, int causal) {
  __shared__ __attribute__((aligned(16))) u16 Kst[2][64 * 64];
  __shared__ __attribute__((aligned(16))) u16 Vt[2][64 * 64];   // [d][k]
  __shared__ __attribute__((aligned(16))) u16 Pl[4][16 * 64];
  const int tid = threadIdx.x;
  const int w = tid >> 6, l = tid & 63, l15 = l & 15, l4 = l >> 4;
  const int lr = l >> 3, lc = l & 7;
  const int kk2 = tid >> 3, dblk = tid & 7;      // V staging role
  const int nqt = Sq / 64;
  const int qt0 = (causal ? (nqt - 1 - (int)blockIdx.x) : (int)blockIdx.x) * 64;
  const int h = blockIdx.y, b = blockIdx.z;
  const u16* Qb = Qp + (size_t)b * Sq * sq + h * DH;
  const u16* Kb = Kp + (size_t)b * Sk * skv + h * DH;
  const u16* Vb = Vp + (size_t)b * Sk * skv + h * DH;

  bf16x8 qf[2];
  {
    int qrow = qt0 + w * 16 + l15;
    const u16* qp0 = Qb + (size_t)qrow * sq + l4 * 8;
    qf[0] = *(const bf16x8*)(qp0);
    qf[1] = *(const bf16x8*)(qp0 + 32);
  }
  f32x4 oacc[4] = {};
  float Mx[4], Ls[4];
#pragma unroll
  for (int r = 0; r < 4; ++r) { Mx[r] = -3e38f; Ls[r] = 0.f; }

  const float CSC = 0.18033688011112042f;  // 1/sqrt(64) * log2(e)
  const int nt = (causal ? (qt0 + 64) : Sk) / 64;

  u16x8 va, vbv;
  auto stageK = [&](int buf, int kt) {
#pragma unroll
    for (int i = 0; i < 2; ++i) {
      int row = i * 32 + w * 8 + lr;
      int sw = lr ^ ((i * 4 + w) & 7);
      const u16* src = Kb + (size_t)(kt + row) * skv + ((lc ^ sw) & 7) * 8;
      __builtin_amdgcn_global_load_lds((const __attribute__((address_space(1))) void*)src,
          (__attribute__((address_space(3))) void*)((char*)Kst[buf] + (i * 32 + w * 8) * 128), 16, 0, 0);
    }
  };
  auto loadV = [&](int kt) {
    const u16* vp0 = Vb + (size_t)(kt + 2 * kk2) * skv + dblk * 8;
    va = *(const u16x8*)vp0;
    vbv = *(const u16x8*)(vp0 + skv);
  };
  auto writeV = [&](int buf) {
    char* Vb_ = (char*)Vt[buf];
#pragma unroll
    for (int j = 0; j < 8; ++j) {
      int d = dblk * 8 + j;
      int sw = (j ^ dblk) & 7;
      unsigned pk = (unsigned)va[j] | ((unsigned)vbv[j] << 16);
      *(unsigned*)(Vb_ + d * 128 + ((4 * kk2) ^ (sw << 4))) = pk;
    }
  };

  // prologue: stage tile 0
  stageK(0, 0);
  loadV(0);
  writeV(0);
  __syncthreads();

  u16* Pw = Pl[w];
  for (int t = 0; t < nt; ++t) {
    const int cur = t & 1;
    if (t + 1 < nt) {              // issue next-tile loads early (T14)
      stageK(cur ^ 1, (t + 1) * 64);
      loadV((t + 1) * 64);
    }
    const u16* KstC = Kst[cur];
    const u16* VtC = Vt[cur];

    // S = Q K^T
    f32x4 sf[4] = {};
#pragma unroll
    for (int n = 0; n < 4; ++n) {
      int rk = n * 16 + l15;
      int sw = (l15 & 7) ^ ((2 * n + (l15 >> 3)) & 7);
#pragma unroll
      for (int ks = 0; ks < 2; ++ks) {
        bf16x8 kf = *(const bf16x8*)&KstC[rk * 64 + ((ks * 32 + l4 * 8) ^ (sw * 8))];
        sf[n] = mfma16(qf[ks], kf, sf[n]);
      }
    }
    if (causal && t == nt - 1) {   // diagonal tile
      int kt = t * 64;
#pragma unroll
      for (int n = 0; n < 4; ++n)
#pragma unroll
        for (int r = 0; r < 4; ++r) {
          int qrow = qt0 + w * 16 + l4 * 4 + r;
          int kcol = kt + n * 16 + l15;
          if (kcol > qrow) sf[n][r] = -3e38f;
        }
    }

    // online softmax
    float al[4];
#pragma unroll
    for (int r = 0; r < 4; ++r) {
      float tm = fmaxf(fmaxf(sf[0][r], sf[1][r]), fmaxf(sf[2][r], sf[3][r]));
      tm = fmaxf(tm, __shfl_xor(tm, 1, 64));
      tm = fmaxf(tm, __shfl_xor(tm, 2, 64));
      tm = fmaxf(tm, __shfl_xor(tm, 4, 64));
      tm = fmaxf(tm, __shfl_xor(tm, 8, 64));
      float Mn = fmaxf(Mx[r], tm);
      al[r] = exp2f((Mx[r] - Mn) * CSC);
      Mx[r] = Mn;
    }
    float rs[4] = {0.f, 0.f, 0.f, 0.f};
#pragma unroll
    for (int n = 0; n < 4; ++n)
#pragma unroll
      for (int r = 0; r < 4; ++r) {
        float p = exp2f((sf[n][r] - Mx[r]) * CSC);
        rs[r] += p;
        int q = l4 * 4 + r;
        int sw = (q & 7) ^ (q >> 3);
        *(u16*)((char*)Pw + q * 128 + ((2 * (n * 16 + l15)) ^ (sw << 4))) = f2b(p);
      }
#pragma unroll
    for (int r = 0; r < 4; ++r) {
      float t2 = rs[r];
      t2 += __shfl_xor(t2, 1, 64);
      t2 += __shfl_xor(t2, 2, 64);
      t2 += __shfl_xor(t2, 4, 64);
      t2 += __shfl_xor(t2, 8, 64);
      Ls[r] = Ls[r] * al[r] + t2;
    }
#pragma unroll
    for (int n2 = 0; n2 < 4; ++n2)
#pragma unroll
      for (int r = 0; r < 4; ++r) oacc[n2][r] *= al[r];

    // P is wave-private: wave-local LDS drain instead of a block barrier
    asm volatile("s_waitcnt lgkmcnt(0)" ::: "memory");
    __builtin_amdgcn_sched_barrier(0);

    // O += P V
    int swp = (l15 & 7) ^ (l15 >> 3);
#pragma unroll
    for (int ks = 0; ks < 2; ++ks) {
      bf16x8 pf = *(const bf16x8*)((char*)Pw + l15 * 128 + ((ks * 64 + l4 * 16) ^ (swp << 4)));
#pragma unroll
      for (int n2 = 0; n2 < 4; ++n2) {
        int rd = n2 * 16 + l15;
        int sw = (l15 & 7) ^ ((2 * n2 + (l15 >> 3)) & 7);
        bf16x8 vf = *(const bf16x8*)((char*)VtC + rd * 128 + ((ks * 64 + l4 * 16) ^ (sw << 4)));
        oacc[n2] = mfma16(pf, vf, oacc[n2]);
      }
    }

    if (t + 1 < nt) writeV(cur ^ 1);   // write-late (vmcnt auto-drained by sync)
    __syncthreads();
  }

  u16* Ob = Op + (size_t)b * Sq * so + h * DH;
#pragma unroll
  for (int n2 = 0; n2 < 4; ++n2)
#pragma unroll
    for (int r = 0; r < 4; ++r) {
      int qrow = qt0 + w * 16 + l4 * 4 + r;
      Ob[(size_t)qrow * so + n2 * 16 + l15] = f2b(oacc[n2][r] / Ls[r]);
    }
}

// ---------------------------------------------------------------------------
// Fused residual + LayerNorm (fp32), dual fp32/bf16 outputs.
// ---------------------------------------------------------------------------
__global__ __launch_bounds__(256) void k_res_ln(const float* __restrict__ xin,
                                                const float* __restrict__ rres,
                                                const float* __restrict__ g,
                                                const float* __restrict__ bet,
                                                float* __restrict__ outf,
                                                u16* __restrict__ outb,
                                                int has_res) {
  __shared__ float red[4];
  const int row = blockIdx.x, tid = threadIdx.x;
  const float* xr = xin + (size_t)row * Ec;
  float v0 = xr[tid], v1 = xr[tid + 256];
  if (has_res) {
    const float* rr = rres + (size_t)row * Ec;
    v0 += rr[tid];
    v1 += rr[tid + 256];
  }
  float s = v0 + v1;
#pragma unroll
  for (int o = 32; o; o >>= 1) s += __shfl_down(s, o, 64);
  if ((tid & 63) == 0) red[tid >> 6] = s;
  __syncthreads();
  const float mean = (red[0] + red[1] + red[2] + red[3]) * (1.f / Ec);
  float d0 = v0 - mean, d1 = v1 - mean;
  float vs = d0 * d0 + d1 * d1;
#pragma unroll
  for (int o = 32; o; o >>= 1) vs += __shfl_down(vs, o, 64);
  __syncthreads();
  if ((tid & 63) == 0) red[tid >> 6] = vs;
  __syncthreads();
  const float var = (red[0] + red[1] + red[2] + red[3]) * (1.f / Ec);
  const float inv = rsqrtf(var + 1e-5f);
  float o0 = d0 * inv * g[tid] + bet[tid];
  float o1 = d1 * inv * g[tid + 256] + bet[tid + 256];
  float* orow = outf + (size_t)row * Ec;
  orow[tid] = o0;
  orow[tid + 256] = o1;
  if (outb) {
    u16* brow = outb + (size_t)row * Ec;
    brow[tid] = f2b(o0);
    brow[tid + 256] = f2b(o1);
  }
}

// ---------------------------------------------------------------------------
extern "C" void kernel_launch(void* const* d_in, const int* in_sizes, int n_in,
                              void* d_out, int out_size, void* d_ws, size_t ws_size,
                              hipStream_t stream) {
  const float* encoded      = (const float*)d_in[0];
  const int*   seq          = (const int*)d_in[1];
  const float* input_embed  = (const float*)d_in[2];
  const float* pos_embed    = (const float*)d_in[3];
  const float* output_bias  = (const float*)d_in[4];
  const float* self_in_w    = (const float*)d_in[5];
  const float* self_in_b    = (const float*)d_in[6];
  const float* self_out_w   = (const float*)d_in[7];
  const float* self_out_b   = (const float*)d_in[8];
  const float* cross_in_w   = (const float*)d_in[9];
  const float* cross_in_b   = (const float*)d_in[10];
  const float* cross_out_w  = (const float*)d_in[11];
  const float* cross_out_b  = (const float*)d_in[12];
  const float* self_norm_g  = (const float*)d_in[13];
  const float* self_norm_b  = (const float*)d_in[14];
  const float* cross_norm_g = (const float*)d_in[15];
  const float* cross_norm_b = (const float*)d_in[16];
  const float* mlp_norm_g   = (const float*)d_in[17];
  const float* mlp_norm_b   = (const float*)d_in[18];
  const float* lin1_w       = (const float*)d_in[19];
  const float* lin1_b       = (const float*)d_in[20];
  const float* lin2_w       = (const float*)d_in[21];
  const float* lin2_b       = (const float*)d_in[22];
  const float* final_norm_g = (const float*)d_in[23];
  const float* final_norm_b = (const float*)d_in[24];

  char* oc = (char*)d_out;
  auto take = [&](size_t bytes) { char* p = oc; oc += bytes; return p; };
  u16* wsi  = (u16*)take((size_t)Lc * 3 * Ec * Ec * 2);
  u16* wso  = (u16*)take((size_t)Lc * Ec * Ec * 2);
  u16* wci  = (u16*)take((size_t)Lc * 3 * Ec * Ec * 2);
  u16* wco  = (u16*)take((size_t)Lc * Ec * Ec * 2);
  u16* wl1  = (u16*)take((size_t)Lc * Fc * Ec * 2);
  u16* wl2  = (u16*)take((size_t)Lc * Ec * Fc * 2);
  u16* encb = (u16*)take((size_t)NMc * Ec * 2);
  float* xs  = (float*)take((size_t)Nc * Ec * 4);
  float* ys  = (float*)take((size_t)Nc * Ec * 4);
  float* tmp = (float*)take((size_t)Nc * Ec * 4);
  u16* xbf  = (u16*)take((size_t)Nc * Ec * 2);
  u16* qkvb = (u16*)take((size_t)Nc * 3 * Ec * 2);
  u16* ctxb = (u16*)take((size_t)Nc * Ec * 2);
  u16* qxb  = (u16*)take((size_t)Nc * Ec * 2);
  u16* kvb  = (u16*)take((size_t)NMc * 2 * Ec * 2);
  u16* hbf  = (u16*)take((size_t)Nc * Fc * 2);
  u16* xfb  = (u16*)d_ws;
  u16* embb = (u16*)((char*)d_ws + (size_t)Nc * Ec * 2);

  const dim3 blk(256);
  auto cvt = [&](const float* s, u16* d, size_t n) {
    int n4 = (int)(n / 4);
    k_cvt<<<dim3((n4 + 255) / 256), blk, 0, stream>>>(s, d, n4);
  };
  cvt(self_in_w, wsi, (size_t)Lc * 3 * Ec * Ec);
  cvt(self_out_w, wso, (size_t)Lc * Ec * Ec);
  cvt(cross_in_w, wci, (size_t)Lc * 3 * Ec * Ec);
  cvt(cross_out_w, wco, (size_t)Lc * Ec * Ec);
  cvt(lin1_w, wl1, (size_t)Lc * Fc * Ec);
  cvt(lin2_w, wl2, (size_t)Lc * Ec * Fc);
  cvt(input_embed, embb, (size_t)Vc * Ec);
  cvt(encoded, encb, (size_t)NMc * Ec);

  k_embed<<<dim3(Nc * Ec / 256), blk, 0, stream>>>(seq, input_embed, pos_embed, xs, xbf);

  const dim3 gAttn(Sc / 64, Hc, Bc);
  for (int l = 0; l < Lc; ++l) {
    const u16* wsi_l = wsi + (size_t)l * 3 * Ec * Ec;
    const u16* wci_l = wci + (size_t)l * 3 * Ec * Ec;
    // self attention
    k_gemm_bf<128, 64, 0><<<dim3(3 * Ec / 64, Nc / 128), blk, 0, stream>>>(
        xbf, wsi_l, self_in_b + (size_t)l * 3 * Ec, nullptr, qkvb, Ec, 3 * Ec);
    k_flash<<<gAttn, blk, 0, stream>>>(qkvb, 3 * Ec, qkvb + Ec, qkvb + 2 * Ec, 3 * Ec,
                                       ctxb, Ec, Sc, Sc, 1);
    k_gemm_bf<64, 64, 0><<<dim3(Ec / 64, Nc / 64), blk, 0, stream>>>(
        ctxb, wso + (size_t)l * Ec * Ec, self_out_b + (size_t)l * Ec, tmp, nullptr, Ec, Ec);
    k_res_ln<<<dim3(Nc), blk, 0, stream>>>(xs, tmp, self_norm_g + (size_t)l * Ec,
                                           self_norm_b + (size_t)l * Ec, ys, xbf, 1);
    // cross attention
    k_gemm_bf<64, 64, 0><<<dim3(Ec / 64, Nc / 64), blk, 0, stream>>>(
        xbf, wci_l, cross_in_b + (size_t)l * 3 * Ec, nullptr, qxb, Ec, Ec);
    k_gemm_bf<64, 64, 0><<<dim3(2 * Ec / 64, NMc / 64), blk, 0, stream>>>(
        encb, wci_l + (size_t)Ec * Ec, cross_in_b + (size_t)l * 3 * Ec + Ec,
        nullptr, kvb, Ec, 2 * Ec);
    k_flash<<<gAttn, blk, 0, stream>>>(qxb, Ec, kvb, kvb + Ec, 2 * Ec,
                                       ctxb, Ec, Sc, Mc, 0);
    k_gemm_bf<64, 64, 0><<<dim3(Ec / 64, Nc / 64), blk, 0, stream>>>(
        ctxb, wco + (size_t)l * Ec * Ec, cross_out_b + (size_t)l * Ec, tmp, nullptr, Ec, Ec);
    k_res_ln<<<dim3(Nc), blk, 0, stream>>>(ys, tmp, cross_norm_g + (size_t)l * Ec,
                                           cross_norm_b + (size_t)l * Ec, xs, xbf, 1);
    // MLP
    k_gemm_bf<128, 64, 1><<<dim3(Fc / 64, Nc / 128), blk, 0, stream>>>(
        xbf, wl1 + (size_t)l * Fc * Ec, lin1_b + (size_t)l * Fc, nullptr, hbf, Ec, Fc);
    k_gemm_bf<64, 64, 0><<<dim3(Ec / 64, Nc / 64), blk, 0, stream>>>(
        hbf, wl2 + (size_t)l * Ec * Fc, lin2_b + (size_t)l * Ec, tmp, nullptr, Fc, Ec);
    k_res_ln<<<dim3(Nc), blk, 0, stream>>>(xs, tmp, mlp_norm_g + (size_t)l * Ec,
                                           mlp_norm_b + (size_t)l * Ec, xs, xbf, 1);
  }

  k_res_ln<<<dim3(Nc), blk, 0, stream>>>(xs, nullptr, final_norm_g, final_norm_b, xs, xfb, 0);
  k_gemm_bf<128, 128, 0><<<dim3(Vc / 128, Nc / 128), blk, 0, stream>>>(
      xfb, embb, output_bias, (float*)d_out, nullptr, Ec, Vc);
}

// Round 4
// 1475.879 us; speedup vs baseline: 15.9437x; 1.0138x over previous
//
#include <hip/hip_runtime.h>
#include <math.h>

typedef unsigned short u16;
typedef __attribute__((ext_vector_type(8))) unsigned short u16x8;
typedef __attribute__((ext_vector_type(8))) __bf16 bf16x8;
typedef __attribute__((ext_vector_type(4))) float f32x4;

constexpr int Bc = 2, Sc = 2048, Mc = 1024, Ec = 512, Hc = 8, DH = 64, Fc = 2048, Vc = 8192, Lc = 6;
constexpr int Nc = Bc * Sc;    // 4096 decoder rows
constexpr int NMc = Bc * Mc;   // 2048 encoder rows

__device__ __forceinline__ u16 f2b(float f) {
  __bf16 h = (__bf16)f;                       // RNE, compiler emits v_cvt_pk_bf16_f32
  return __builtin_bit_cast(u16, h);
}

__device__ __forceinline__ f32x4 mfma16(bf16x8 a, bf16x8 b, f32x4 c) {
  return __builtin_amdgcn_mfma_f32_16x16x32_bf16(a, b, c, 0, 0, 0);
}

// ---------------------------------------------------------------------------
// f32 -> bf16 bulk convert
// ---------------------------------------------------------------------------
__global__ __launch_bounds__(256) void k_cvt(const float* __restrict__ s,
                                             u16* __restrict__ d, int n4) {
  int i = blockIdx.x * 256 + threadIdx.x;
  if (i >= n4) return;
  float4 v = ((const float4*)s)[i];
  unsigned lo = (unsigned)f2b(v.x) | ((unsigned)f2b(v.y) << 16);
  unsigned hi = (unsigned)f2b(v.z) | ((unsigned)f2b(v.w) << 16);
  ((uint2*)d)[i] = make_uint2(lo, hi);
}

// ---------------------------------------------------------------------------
// Embedding: fp32 + bf16 outputs
// ---------------------------------------------------------------------------
__global__ __launch_bounds__(256) void k_embed(const int* __restrict__ seq,
                                               const float* __restrict__ emb,
                                               const float* __restrict__ pos,
                                               float* __restrict__ x,
                                               u16* __restrict__ xb) {
  int idx = blockIdx.x * 256 + threadIdx.x;
  int row = idx >> 9, e = idx & 511;
  int s = row & (Sc - 1);
  float v = emb[(size_t)seq[row] * Ec + e] + pos[(size_t)s * Ec + e];
  x[idx] = v;
  xb[idx] = f2b(v);
}

// ---------------------------------------------------------------------------
// bf16 MFMA GEMM, swizzled LDS, staged via global_load_lds (pre-swizzled src).
// Tiles BM x BN, BK=64, 4 waves in 2x2 quadrants.
// ---------------------------------------------------------------------------
template <int BM, int BN, int ACT>
__global__ __launch_bounds__(256) void k_gemm_bf(const u16* __restrict__ A,
                                                 const u16* __restrict__ W,
                                                 const float* __restrict__ bias,
                                                 float* __restrict__ C32,
                                                 u16* __restrict__ Cb,
                                                 int K, int Mo) {
  constexpr int WM = BM / 2, WN = BN / 2, FM = WM / 16, FN = WN / 16;
  __shared__ __attribute__((aligned(16))) u16 As[BM * 64];
  __shared__ __attribute__((aligned(16))) u16 Bs[BN * 64];
  const int tid = threadIdx.x;
  const int w = tid >> 6, l = tid & 63, l15 = l & 15, l4 = l >> 4;
  const int lr = l >> 3, lc = l & 7;
  const int wr = (w >> 1) * WM, wc = (w & 1) * WN;
  const size_t row0 = (size_t)blockIdx.y * BM, col0 = (size_t)blockIdx.x * BN;
  const u16* Ab = A + row0 * K;
  const u16* Wb = W + col0 * K;
  f32x4 acc[FM][FN] = {};

  for (int k0 = 0; k0 < K; k0 += 64) {
    __syncthreads();
#pragma unroll
    for (int i = 0; i < BM / 32; ++i) {
      int row = i * 32 + w * 8 + lr;
      int sw = lr ^ ((i * 4 + w) & 7);
      const u16* ga = Ab + (size_t)row * K + k0 + ((lc ^ sw) & 7) * 8;
      __builtin_amdgcn_global_load_lds((const __attribute__((address_space(1))) void*)ga,
          (__attribute__((address_space(3))) void*)((char*)As + (i * 32 + w * 8) * 128), 16, 0, 0);
    }
#pragma unroll
    for (int i = 0; i < BN / 32; ++i) {
      int row = i * 32 + w * 8 + lr;
      int sw = lr ^ ((i * 4 + w) & 7);
      const u16* gw = Wb + (size_t)row * K + k0 + ((lc ^ sw) & 7) * 8;
      __builtin_amdgcn_global_load_lds((const __attribute__((address_space(1))) void*)gw,
          (__attribute__((address_space(3))) void*)((char*)Bs + (i * 32 + w * 8) * 128), 16, 0, 0);
    }
    __syncthreads();
#pragma unroll
    for (int ks = 0; ks < 2; ++ks) {
      bf16x8 af[FM], bfr[FN];
#pragma unroll
      for (int m = 0; m < FM; ++m) {
        int ra = wr + m * 16 + l15;
        int sw = (l15 & 7) ^ ((wr / 8 + 2 * m + (l15 >> 3)) & 7);
        af[m] = *(const bf16x8*)&As[ra * 64 + ((ks * 32 + l4 * 8) ^ (sw * 8))];
      }
#pragma unroll
      for (int n = 0; n < FN; ++n) {
        int rb = wc + n * 16 + l15;
        int sw = (l15 & 7) ^ ((wc / 8 + 2 * n + (l15 >> 3)) & 7);
        bfr[n] = *(const bf16x8*)&Bs[rb * 64 + ((ks * 32 + l4 * 8) ^ (sw * 8))];
      }
#pragma unroll
      for (int m = 0; m < FM; ++m)
#pragma unroll
        for (int n = 0; n < FN; ++n)
          acc[m][n] = mfma16(af[m], bfr[n], acc[m][n]);
    }
  }
#pragma unroll
  for (int n = 0; n < FN; ++n) {
    size_t col = col0 + wc + n * 16 + l15;
    float bv = bias[col];
#pragma unroll
    for (int m = 0; m < FM; ++m)
#pragma unroll
      for (int r = 0; r < 4; ++r) {
        size_t row = row0 + wr + m * 16 + l4 * 4 + r;
        float v = acc[m][n][r] + bv;
        if (ACT) v = 0.5f * v * (1.f + erff(v * 0.70710678118654752f));
        if (C32) C32[row * Mo + col] = v;
        if (Cb) Cb[row * Mo + col] = f2b(v);
      }
  }
}

// ---------------------------------------------------------------------------
// Flash attention, bf16 MFMA. 3-deep K/V pipeline, counted waits, raw barrier.
// Grid (Sq/64, H, B), 256 thr = 4 waves; wave w owns q rows [qt0+16w, +16).
// Row-sum via mfma(P, ones); defer-rescale when row max unchanged (exact).
// ---------------------------------------------------------------------------
__global__ __launch_bounds__(256) void k_flash(const u16* __restrict__ Qp, int sq,
                                               const u16* __restrict__ Kp,
                                               const u16* __restrict__ Vp, int skv,
                                               u16* __restrict__ Op, int so,
                                               int Sq, int Sk, int causal) {
  __shared__ __attribute__((aligned(16))) u16 Kst[3][64 * 64];
  __shared__ __attribute__((aligned(16))) u16 Vt[3][64 * 64];   // [d][k]
  __shared__ __attribute__((aligned(16))) u16 Pl[4][16 * 64];
  const int tid = threadIdx.x;
  const int w = tid >> 6, l = tid & 63, l15 = l & 15, l4 = l >> 4;
  const int lr = l >> 3, lc = l & 7;
  const int kk2 = tid >> 3, dblk = tid & 7;      // V staging role
  const int nqt = Sq / 64;
  const int qt0 = (causal ? (nqt - 1 - (int)blockIdx.x) : (int)blockIdx.x) * 64;
  const int h = blockIdx.y, b = blockIdx.z;
  const u16* Qb = Qp + (size_t)b * Sq * sq + h * DH;
  const u16* Kb = Kp + (size_t)b * Sk * skv + h * DH;
  const u16* Vb = Vp + (size_t)b * Sk * skv + h * DH;

  bf16x8 qf[2];
  {
    int qrow = qt0 + w * 16 + l15;
    const u16* qp0 = Qb + (size_t)qrow * sq + l4 * 8;
    qf[0] = *(const bf16x8*)(qp0);
    qf[1] = *(const bf16x8*)(qp0 + 32);
  }
  bf16x8 onesf;
#pragma unroll
  for (int j = 0; j < 8; ++j) onesf[j] = (__bf16)1.0f;

  f32x4 oacc[4] = {};
  f32x4 lsacc = {0.f, 0.f, 0.f, 0.f};
  float Mx[4];
#pragma unroll
  for (int r = 0; r < 4; ++r) Mx[r] = -3e38f;

  const float CSC = 0.18033688011112042f;  // 1/sqrt(64) * log2(e)
  const int nt = (causal ? (qt0 + 64) : Sk) / 64;

  u16x8 va0, vb0, va1, vb1;
  auto stageK = [&](int buf, int kt) {
#pragma unroll
    for (int i = 0; i < 2; ++i) {
      int row = i * 32 + w * 8 + lr;
      int sw = lr ^ ((i * 4 + w) & 7);
      const u16* src = Kb + (size_t)(kt + row) * skv + ((lc ^ sw) & 7) * 8;
      __builtin_amdgcn_global_load_lds((const __attribute__((address_space(1))) void*)src,
          (__attribute__((address_space(3))) void*)((char*)Kst[buf] + (i * 32 + w * 8) * 128), 16, 0, 0);
    }
  };
  auto loadV = [&](int kt, u16x8& a, u16x8& bv) {
    const u16* vp0 = Vb + (size_t)(kt + 2 * kk2) * skv + dblk * 8;
    a = *(const u16x8*)vp0;
    bv = *(const u16x8*)(vp0 + skv);
  };
  auto writeV = [&](int buf, u16x8 a, u16x8 bv) {
    char* Vb_ = (char*)Vt[buf];
#pragma unroll
    for (int j = 0; j < 8; ++j) {
      int d = dblk * 8 + j;
      int sw = (j ^ dblk) & 7;
      unsigned pk = (unsigned)a[j] | ((unsigned)bv[j] << 16);
      *(unsigned*)(Vb_ + d * 128 + ((4 * kk2) ^ (sw << 4))) = pk;
    }
  };

  // prologue: tiles 0 (and 1) in flight; V(0) set0, V(1) set1
  stageK(0, 0);
  loadV(0, va0, vb0);
  if (nt > 1) { stageK(1, 64); loadV(64, va1, vb1); }
  writeV(0, va0, vb0);   // implicit vmcnt wait covers K(0) too (older in queue)
  asm volatile("s_waitcnt lgkmcnt(0)" ::: "memory");
  __builtin_amdgcn_sched_barrier(0);
  __builtin_amdgcn_s_barrier();

  u16* Pw = Pl[w];
  int cur = 0;
  for (int t = 0; t < nt; ++t) {
    const int nxt = (cur == 2) ? 0 : cur + 1;
    const int nn  = (nxt == 2) ? 0 : nxt + 1;
    if (t + 2 < nt) {              // issue tile t+2 (K->LDS, V->regs, set t%2)
      stageK(nn, (t + 2) * 64);
      if (t & 1) loadV((t + 2) * 64, va1, vb1);
      else       loadV((t + 2) * 64, va0, vb0);
    }
    const u16* KstC = Kst[cur];
    const u16* VtC = Vt[cur];

    // S = Q K^T
    f32x4 sf[4] = {};
    __builtin_amdgcn_s_setprio(1);
#pragma unroll
    for (int n = 0; n < 4; ++n) {
      int rk = n * 16 + l15;
      int sw = (l15 & 7) ^ ((2 * n + (l15 >> 3)) & 7);
#pragma unroll
      for (int ks = 0; ks < 2; ++ks) {
        bf16x8 kf = *(const bf16x8*)&KstC[rk * 64 + ((ks * 32 + l4 * 8) ^ (sw * 8))];
        sf[n] = mfma16(qf[ks], kf, sf[n]);
      }
    }
    __builtin_amdgcn_s_setprio(0);

    if (causal && t == nt - 1) {   // diagonal tile
      int kt = t * 64;
#pragma unroll
      for (int n = 0; n < 4; ++n)
#pragma unroll
        for (int r = 0; r < 4; ++r) {
          int qrow = qt0 + w * 16 + l4 * 4 + r;
          int kcol = kt + n * 16 + l15;
          if (kcol > qrow) sf[n][r] = -3e38f;
        }
    }

    // online softmax: new row max across 16-lane col groups
    float al[4];
#pragma unroll
    for (int r = 0; r < 4; ++r) {
      float tm = fmaxf(fmaxf(sf[0][r], sf[1][r]), fmaxf(sf[2][r], sf[3][r]));
      tm = fmaxf(tm, __shfl_xor(tm, 1, 64));
      tm = fmaxf(tm, __shfl_xor(tm, 2, 64));
      tm = fmaxf(tm, __shfl_xor(tm, 4, 64));
      tm = fmaxf(tm, __shfl_xor(tm, 8, 64));
      float Mn = fmaxf(Mx[r], tm);
      al[r] = exp2f((Mx[r] - Mn) * CSC);   // == 1.0 exactly when no growth
      Mx[r] = Mn;
    }
    // P = exp2((S - Mx)*CSC), written to wave-private LDS
    float mxc[4];
#pragma unroll
    for (int r = 0; r < 4; ++r) mxc[r] = Mx[r] * CSC;
#pragma unroll
    for (int n = 0; n < 4; ++n)
#pragma unroll
      for (int r = 0; r < 4; ++r) {
        float p = exp2f(sf[n][r] * CSC - mxc[r]);
        int q = l4 * 4 + r;
        int sw = (q & 7) ^ (q >> 3);
        *(u16*)((char*)Pw + q * 128 + ((2 * (n * 16 + l15)) ^ (sw << 4))) = f2b(p);
      }
    // defer-rescale: skip O/L rescale when no row max grew (exact, al==1)
    bool grow = (al[0] < 1.f) | (al[1] < 1.f) | (al[2] < 1.f) | (al[3] < 1.f);
    if (__any(grow)) {
#pragma unroll
      for (int r = 0; r < 4; ++r) {
        lsacc[r] *= al[r];
#pragma unroll
        for (int n2 = 0; n2 < 4; ++n2) oacc[n2][r] *= al[r];
      }
    }

    // P is wave-private: wave-local LDS drain instead of a block barrier
    asm volatile("s_waitcnt lgkmcnt(0)" ::: "memory");
    __builtin_amdgcn_sched_barrier(0);

    // O += P V ; rowsum += P * ones
    int swp = (l15 & 7) ^ (l15 >> 3);
    __builtin_amdgcn_s_setprio(1);
#pragma unroll
    for (int ks = 0; ks < 2; ++ks) {
      bf16x8 pf = *(const bf16x8*)((char*)Pw + l15 * 128 + ((ks * 64 + l4 * 16) ^ (swp << 4)));
      lsacc = mfma16(pf, onesf, lsacc);
#pragma unroll
      for (int n2 = 0; n2 < 4; ++n2) {
        int rd = n2 * 16 + l15;
        int sw = (l15 & 7) ^ ((2 * n2 + (l15 >> 3)) & 7);
        bf16x8 vf = *(const bf16x8*)((char*)VtC + rd * 128 + ((ks * 64 + l4 * 16) ^ (sw << 4)));
        oacc[n2] = mfma16(pf, vf, oacc[n2]);
      }
    }
    __builtin_amdgcn_s_setprio(0);

    if (t + 1 < nt) {              // write V(t+1) late; its vmcnt wait also
      if (t & 1) writeV(nxt, va0, vb0);   // guarantees K(t+1) landed (older)
      else       writeV(nxt, va1, vb1);
    }
    asm volatile("s_waitcnt lgkmcnt(0)" ::: "memory");
    __builtin_amdgcn_sched_barrier(0);
    __builtin_amdgcn_s_barrier();
    cur = nxt;
  }

  u16* Ob = Op + (size_t)b * Sq * so + h * DH;
#pragma unroll
  for (int n2 = 0; n2 < 4; ++n2)
#pragma unroll
    for (int r = 0; r < 4; ++r) {
      int qrow = qt0 + w * 16 + l4 * 4 + r;
      Ob[(size_t)qrow * so + n2 * 16 + l15] = f2b(oacc[n2][r] / lsacc[r]);
    }
}

// ---------------------------------------------------------------------------
// Fused residual + LayerNorm (fp32), dual fp32/bf16 outputs.
// ---------------------------------------------------------------------------
__global__ __launch_bounds__(256) void k_res_ln(const float* __restrict__ xin,
                                                const float* __restrict__ rres,
                                                const float* __restrict__ g,
                                                const float* __restrict__ bet,
                                                float* __restrict__ outf,
                                                u16* __restrict__ outb,
                                                int has_res) {
  __shared__ float red[4];
  const int row = blockIdx.x, tid = threadIdx.x;
  const float* xr = xin + (size_t)row * Ec;
  float v0 = xr[tid], v1 = xr[tid + 256];
  if (has_res) {
    const float* rr = rres + (size_t)row * Ec;
    v0 += rr[tid];
    v1 += rr[tid + 256];
  }
  float s = v0 + v1;
#pragma unroll
  for (int o = 32; o; o >>= 1) s += __shfl_down(s, o, 64);
  if ((tid & 63) == 0) red[tid >> 6] = s;
  __syncthreads();
  const float mean = (red[0] + red[1] + red[2] + red[3]) * (1.f / Ec);
  float d0 = v0 - mean, d1 = v1 - mean;
  float vs = d0 * d0 + d1 * d1;
#pragma unroll
  for (int o = 32; o; o >>= 1) vs += __shfl_down(vs, o, 64);
  __syncthreads();
  if ((tid & 63) == 0) red[tid >> 6] = vs;
  __syncthreads();
  const float var = (red[0] + red[1] + red[2] + red[3]) * (1.f / Ec);
  const float inv = rsqrtf(var + 1e-5f);
  float o0 = d0 * inv * g[tid] + bet[tid];
  float o1 = d1 * inv * g[tid + 256] + bet[tid + 256];
  float* orow = outf + (size_t)row * Ec;
  orow[tid] = o0;
  orow[tid + 256] = o1;
  if (outb) {
    u16* brow = outb + (size_t)row * Ec;
    brow[tid] = f2b(o0);
    brow[tid + 256] = f2b(o1);
  }
}

// ---------------------------------------------------------------------------
extern "C" void kernel_launch(void* const* d_in, const int* in_sizes, int n_in,
                              void* d_out, int out_size, void* d_ws, size_t ws_size,
                              hipStream_t stream) {
  const float* encoded      = (const float*)d_in[0];
  const int*   seq          = (const int*)d_in[1];
  const float* input_embed  = (const float*)d_in[2];
  const float* pos_embed    = (const float*)d_in[3];
  const float* output_bias  = (const float*)d_in[4];
  const float* self_in_w    = (const float*)d_in[5];
  const float* self_in_b    = (const float*)d_in[6];
  const float* self_out_w   = (const float*)d_in[7];
  const float* self_out_b   = (const float*)d_in[8];
  const float* cross_in_w   = (const float*)d_in[9];
  const float* cross_in_b   = (const float*)d_in[10];
  const float* cross_out_w  = (const float*)d_in[11];
  const float* cross_out_b  = (const float*)d_in[12];
  const float* self_norm_g  = (const float*)d_in[13];
  const float* self_norm_b  = (const float*)d_in[14];
  const float* cross_norm_g = (const float*)d_in[15];
  const float* cross_norm_b = (const float*)d_in[16];
  const float* mlp_norm_g   = (const float*)d_in[17];
  const float* mlp_norm_b   = (const float*)d_in[18];
  const float* lin1_w       = (const float*)d_in[19];
  const float* lin1_b       = (const float*)d_in[20];
  const float* lin2_w       = (const float*)d_in[21];
  const float* lin2_b       = (const float*)d_in[22];
  const float* final_norm_g = (const float*)d_in[23];
  const float* final_norm_b = (const float*)d_in[24];

  char* oc = (char*)d_out;
  auto take = [&](size_t bytes) { char* p = oc; oc += bytes; return p; };
  u16* wsi  = (u16*)take((size_t)Lc * 3 * Ec * Ec * 2);
  u16* wso  = (u16*)take((size_t)Lc * Ec * Ec * 2);
  u16* wci  = (u16*)take((size_t)Lc * 3 * Ec * Ec * 2);
  u16* wco  = (u16*)take((size_t)Lc * Ec * Ec * 2);
  u16* wl1  = (u16*)take((size_t)Lc * Fc * Ec * 2);
  u16* wl2  = (u16*)take((size_t)Lc * Ec * Fc * 2);
  u16* encb = (u16*)take((size_t)NMc * Ec * 2);
  float* xs  = (float*)take((size_t)Nc * Ec * 4);
  float* ys  = (float*)take((size_t)Nc * Ec * 4);
  float* tmp = (float*)take((size_t)Nc * Ec * 4);
  u16* xbf  = (u16*)take((size_t)Nc * Ec * 2);
  u16* qkvb = (u16*)take((size_t)Nc * 3 * Ec * 2);
  u16* ctxb = (u16*)take((size_t)Nc * Ec * 2);
  u16* qxb  = (u16*)take((size_t)Nc * Ec * 2);
  u16* kvb  = (u16*)take((size_t)NMc * 2 * Ec * 2);
  u16* hbf  = (u16*)take((size_t)Nc * Fc * 2);
  u16* xfb  = (u16*)d_ws;
  u16* embb = (u16*)((char*)d_ws + (size_t)Nc * Ec * 2);

  const dim3 blk(256);
  auto cvt = [&](const float* s, u16* d, size_t n) {
    int n4 = (int)(n / 4);
    k_cvt<<<dim3((n4 + 255) / 256), blk, 0, stream>>>(s, d, n4);
  };
  cvt(self_in_w, wsi, (size_t)Lc * 3 * Ec * Ec);
  cvt(self_out_w, wso, (size_t)Lc * Ec * Ec);
  cvt(cross_in_w, wci, (size_t)Lc * 3 * Ec * Ec);
  cvt(cross_out_w, wco, (size_t)Lc * Ec * Ec);
  cvt(lin1_w, wl1, (size_t)Lc * Fc * Ec);
  cvt(lin2_w, wl2, (size_t)Lc * Ec * Fc);
  cvt(input_embed, embb, (size_t)Vc * Ec);
  cvt(encoded, encb, (size_t)NMc * Ec);

  k_embed<<<dim3(Nc * Ec / 256), blk, 0, stream>>>(seq, input_embed, pos_embed, xs, xbf);

  const dim3 gAttn(Sc / 64, Hc, Bc);
  for (int l = 0; l < Lc; ++l) {
    const u16* wsi_l = wsi + (size_t)l * 3 * Ec * Ec;
    const u16* wci_l = wci + (size_t)l * 3 * Ec * Ec;
    // self attention
    k_gemm_bf<128, 64, 0><<<dim3(3 * Ec / 64, Nc / 128), blk, 0, stream>>>(
        xbf, wsi_l, self_in_b + (size_t)l * 3 * Ec, nullptr, qkvb, Ec, 3 * Ec);
    k_flash<<<gAttn, blk, 0, stream>>>(qkvb, 3 * Ec, qkvb + Ec, qkvb + 2 * Ec, 3 * Ec,
                                       ctxb, Ec, Sc, Sc, 1);
    k_gemm_bf<64, 64, 0><<<dim3(Ec / 64, Nc / 64), blk, 0, stream>>>(
        ctxb, wso + (size_t)l * Ec * Ec, self_out_b + (size_t)l * Ec, tmp, nullptr, Ec, Ec);
    k_res_ln<<<dim3(Nc), blk, 0, stream>>>(xs, tmp, self_norm_g + (size_t)l * Ec,
                                           self_norm_b + (size_t)l * Ec, ys, xbf, 1);
    // cross attention
    k_gemm_bf<64, 64, 0><<<dim3(Ec / 64, Nc / 64), blk, 0, stream>>>(
        xbf, wci_l, cross_in_b + (size_t)l * 3 * Ec, nullptr, qxb, Ec, Ec);
    k_gemm_bf<64, 64, 0><<<dim3(2 * Ec / 64, NMc / 64), blk, 0, stream>>>(
        encb, wci_l + (size_t)Ec * Ec, cross_in_b + (size_t)l * 3 * Ec + Ec,
        nullptr, kvb, Ec, 2 * Ec);
    k_flash<<<gAttn, blk, 0, stream>>>(qxb, Ec, kvb, kvb + Ec, 2 * Ec,
                                       ctxb, Ec, Sc, Mc, 0);
    k_gemm_bf<64, 64, 0><<<dim3(Ec / 64, Nc / 64), blk, 0, stream>>>(
        ctxb, wco + (size_t)l * Ec * Ec, cross_out_b + (size_t)l * Ec, tmp, nullptr, Ec, Ec);
    k_res_ln<<<dim3(Nc), blk, 0, stream>>>(ys, tmp, cross_norm_g + (size_t)l * Ec,
                                           cross_norm_b + (size_t)l * Ec, xs, xbf, 1);
    // MLP
    k_gemm_bf<128, 64, 1><<<dim3(Fc / 64, Nc / 128), blk, 0, stream>>>(
        xbf, wl1 + (size_t)l * Fc * Ec, lin1_b + (size_t)l * Fc, nullptr, hbf, Ec, Fc);
    k_gemm_bf<64, 64, 0><<<dim3(Ec / 64, Nc / 64), blk, 0, stream>>>(
        hbf, wl2 + (size_t)l * Ec * Fc, lin2_b + (size_t)l * Ec, tmp, nullptr, Fc, Ec);
    k_res_ln<<<dim3(Nc), blk, 0, stream>>>(xs, tmp, mlp_norm_g + (size_t)l * Ec,
                                           mlp_norm_b + (size_t)l * Ec, xs, xbf, 1);
  }

  k_res_ln<<<dim3(Nc), blk, 0, stream>>>(xs, nullptr, final_norm_g, final_norm_b, xs, xfb, 0);
  k_gemm_bf<128, 128, 0><<<dim3(Vc / 128, Nc / 128), blk, 0, stream>>>(
      xfb, embb, output_bias, (float*)d_out, nullptr, Ec, Vc);
}